// Round 6
// baseline (58.866 us; speedup 1.0000x reference)
//
#include <hip/hip_runtime.h>
#include <cmath>

// Fixed problem shape (reference setup_inputs): bs=16, nq=900, nc=80, nt=3200
#define NCC   80                 // classes
#define QT    8                  // queries per row-group
#define BLK   256                // threads per block
#define VT    4                  // targets per thread (float4 store)
#define NT_C  3200               // targets
#define NQB_C 14400              // bs*nq rows
#define CPR   (NT_C / VT)        // 800 float4-columns per row-group
#define NRG   (NQB_C / QT)       // 1800 row-groups
#define CSTR  20                 // class-table row stride in floats (16B-aligned)

typedef float f32x4 __attribute__((ext_vector_type(4)));

__device__ __forceinline__ float cls_cost(float x) {
    // 2*(pos-neg) + 2  : COST_CLASS folded + giou-rewrite constant
    const float p   = 1.0f / (1.0f + __expf(-x));
    const float om  = 1.0f - p;
    const float pos = 0.25f * om * om * (-__logf(p  + 1e-8f));
    const float neg = 0.75f * p  * p  * (-__logf(om + 1e-8f));
    return 2.0f * (pos - neg) + 2.0f;
}

// ---- pre-kernel: class-cost table [row][class] into workspace ---------------
__global__ __launch_bounds__(256) void cls_table_kernel(
    const float* __restrict__ logits, float* __restrict__ tbl)
{
    const int i = blockIdx.x * 256 + threadIdx.x;   // grid sized exactly
    tbl[i] = cls_cost(logits[i]);
}

// ---------------- fast kernel ----------------------------------------------
__global__ __launch_bounds__(BLK) void cost_fast(
    const float* __restrict__ tbl,      // precomputed table, or nullptr
    const float* __restrict__ logits,   // [NQB_C, NCC]
    const float* __restrict__ pboxes,   // [NQB_C, 4] cxcywh
    const int*   __restrict__ labels,   // [NT_C]
    const float* __restrict__ tboxes,   // [NT_C, 4] cxcywh
    float*       __restrict__ out)      // [NQB_C, NT_C]
{
    __shared__ float4 s_clsv[NCC * (CSTR / 4)];     // [80][20] floats
    __shared__ float4 s_qb[2 * QT];                 // cxcywh
    __shared__ float4 s_qx[2 * QT];                 // xyxy
    __shared__ float  s_qa[2 * QT];                 // area
    float* s_cls = (float*)s_clsv;

    const int w0   = blockIdx.x * BLK;
    const int rg0  = w0 / CPR;
    const int row0 = rg0 * QT;

    // Stage transposed class table [lab][row-in-16]; rows clamped at the end.
    if (tbl != nullptr) {
        for (int t = threadIdx.x; t < 16 * NCC; t += BLK) {
            const int qi  = t / NCC;                 // 0..15
            const int lab = t - qi * NCC;
            const int row = min(row0 + qi, NQB_C - 1);
            s_cls[lab * CSTR + qi] = tbl[row * NCC + lab];   // coalesced read
        }
    } else {
        for (int t = threadIdx.x; t < 16 * NCC; t += BLK) {
            const int qi  = t / NCC;
            const int lab = t - qi * NCC;
            const int row = min(row0 + qi, NQB_C - 1);
            s_cls[lab * CSTR + qi] = cls_cost(logits[row * NCC + lab]);
        }
    }
    // Stage query geometry (16 rows, clamped)
    if (threadIdx.x < 2 * QT) {
        const int row = min(row0 + (int)threadIdx.x, NQB_C - 1);
        const float4 b = ((const float4*)pboxes)[row];
        s_qb[threadIdx.x] = b;
        s_qx[threadIdx.x] = make_float4(b.x - 0.5f * b.z, b.y - 0.5f * b.w,
                                        b.x + 0.5f * b.z, b.y + 0.5f * b.w);
        s_qa[threadIdx.x] = b.z * b.w;
    }
    __syncthreads();

    const int w  = w0 + threadIdx.x;
    const int rg = w / CPR;
    const int c  = w - rg * CPR;
    const int j  = c * VT;
    const int g8 = (rg - rg0) * QT;          // 0 or 8

    // Per-thread target data
    const int4 lab4 = ((const int4*)labels)[c];
    const int labk[VT] = { lab4.x, lab4.y, lab4.z, lab4.w };
    float4 tb[VT];
    float tx0[VT], ty0[VT], tx1[VT], ty1[VT], ta[VT];
#pragma unroll
    for (int k = 0; k < VT; ++k) {
        tb[k]  = ((const float4*)tboxes)[j + k];
        tx0[k] = tb[k].x - 0.5f * tb[k].z;  tx1[k] = tb[k].x + 0.5f * tb[k].z;
        ty0[k] = tb[k].y - 0.5f * tb[k].w;  ty1[k] = tb[k].y + 0.5f * tb[k].w;
        ta[k]  = tb[k].z * tb[k].w;
    }

    const unsigned obase = (unsigned)(rg * QT) * NT_C + (unsigned)j;

    // Two halves of 4 queries — NOT unrolled, to cap live registers.
#pragma unroll 1
    for (int h = 0; h < 2; ++h) {
        const int qbase = g8 + h * 4;
        float4 c2v[VT];
#pragma unroll
        for (int k = 0; k < VT; ++k)
            c2v[k] = *(const float4*)&s_cls[labk[k] * CSTR + qbase];

        const unsigned offh = obase + (unsigned)h * 4u * NT_C;
#pragma unroll
        for (int q4 = 0; q4 < 4; ++q4) {
            const int    qi = qbase + q4;
            const float4 qb = s_qb[qi];
            const float4 qx = s_qx[qi];
            const float  qa = s_qa[qi];
            float res[VT];
#pragma unroll
            for (int k = 0; k < VT; ++k) {
                const float c2 = c2v[k][q4];
                // signed intersection extents
                const float dx = fminf(qx.z, tx1[k]) - fmaxf(qx.x, tx0[k]);
                const float dy = fminf(qx.w, ty1[k]) - fmaxf(qx.y, ty0[k]);
                const float iw = fmaxf(dx, 0.0f);
                const float ih = fmaxf(dy, 0.0f);
                const float inter = iw * ih;
                const float uni   = (qa + ta[k]) - inter;
                // enclosure via max = a+b-min  (>= 0 by construction)
                const float ew = (qb.z + tb[k].z) - dx;
                const float eh = (qb.w + tb[k].w) - dy;
                const float encl = ew * eh;
                // merged single-division:
                //   inter/ug + uni/eg = (inter*eg + uni*ug) / (ug*eg)
                const float ug  = fmaxf(uni,  1e-6f);
                const float eg  = fmaxf(encl, 1e-6f);
                const float num = fmaf(uni, ug, inter * eg);
                const float r   = __builtin_amdgcn_rcpf(ug * eg);
                const float l1 = (fabsf(qb.x - tb[k].x) + fabsf(qb.y - tb[k].y))
                               + (fabsf(qb.z - tb[k].z) + fabsf(qb.w - tb[k].w));
                // C = 5*l1 + (2*cls+2) - 2*(inter/uni + uni/encl)
                float cc = fmaf(5.0f, l1, c2);
                cc = fmaf(num * r, -2.0f, cc);
                res[k] = cc;
            }
            f32x4 v = { res[0], res[1], res[2], res[3] };
            __builtin_nontemporal_store(
                v, (f32x4*)(out + offh + (unsigned)q4 * NT_C));
        }
    }
}

// ---------------- generic fallback ------------------------------------------
__global__ __launch_bounds__(BLK) void cost_generic(
    const float* __restrict__ logits, const float* __restrict__ pboxes,
    const int* __restrict__ labels, const float* __restrict__ tboxes,
    float* __restrict__ out, int NQB, int NT, int NC)
{
    extern __shared__ float smem[];
    float*  s_cls = smem;                  // QT*NC
    float4* s_qb  = (float4*)(smem + QT * NC);

    const int i0 = blockIdx.y * QT;
    const int j  = blockIdx.x * BLK + threadIdx.x;

    for (int t = threadIdx.x; t < QT * NC; t += BLK) {
        const int qi = i0 + t / NC;
        float v = 0.0f;
        if (qi < NQB) {
            const float x  = logits[qi * NC + (t % NC)];
            const float p  = 1.0f / (1.0f + __expf(-x));
            const float om = 1.0f - p;
            v = 0.25f * om * om * (-__logf(p + 1e-8f))
              - 0.75f * p * p * (-__logf(om + 1e-8f));
        }
        s_cls[t] = v;
    }
    if (threadIdx.x < QT) {
        const int qi = i0 + threadIdx.x;
        s_qb[threadIdx.x] = (qi < NQB) ? ((const float4*)pboxes)[qi]
                                       : make_float4(0.f, 0.f, 0.f, 0.f);
    }
    __syncthreads();
    if (j >= NT) return;

    const float4 tb = ((const float4*)tboxes)[j];
    const int   lab = labels[j];
    const float tx0 = tb.x - 0.5f * tb.z, tx1 = tb.x + 0.5f * tb.z;
    const float ty0 = tb.y - 0.5f * tb.w, ty1 = tb.y + 0.5f * tb.w;
    const float ta  = tb.z * tb.w;

#pragma unroll
    for (int q = 0; q < QT; ++q) {
        const float4 qb = s_qb[q];
        const float ccls = s_cls[q * NC + lab];
        const float l1 = fabsf(qb.x - tb.x) + fabsf(qb.y - tb.y)
                       + fabsf(qb.z - tb.z) + fabsf(qb.w - tb.w);
        const float qx0 = qb.x - 0.5f * qb.z, qx1 = qb.x + 0.5f * qb.z;
        const float qy0 = qb.y - 0.5f * qb.w, qy1 = qb.y + 0.5f * qb.w;
        const float qa  = qb.z * qb.w;
        const float ltx = fmaxf(qx0, tx0), lty = fmaxf(qy0, ty0);
        const float rbx = fminf(qx1, tx1), rby = fminf(qy1, ty1);
        const float iw = fmaxf(rbx - ltx, 0.f), ih = fmaxf(rby - lty, 0.f);
        const float inter = iw * ih;
        const float uni   = qa + ta - inter;
        const float iou   = inter * __builtin_amdgcn_rcpf(fmaxf(uni, 1e-6f));
        const float ex0 = fminf(qx0, tx0), ey0 = fminf(qy0, ty0);
        const float ex1 = fmaxf(qx1, tx1), ey1 = fmaxf(qy1, ty1);
        const float ew = fmaxf(ex1 - ex0, 0.f), eh = fmaxf(ey1 - ey0, 0.f);
        const float encl = ew * eh;
        const float giou = iou - (encl - uni) * __builtin_amdgcn_rcpf(fmaxf(encl, 1e-6f));
        float cc = 5.0f * l1 + 2.0f * ccls - 2.0f * giou;
        cc = (cc == cc) ? cc : 1.0f;
        const int qi = i0 + q;
        if (qi < NQB) out[(size_t)qi * NT + j] = cc;
    }
}

extern "C" void kernel_launch(void* const* d_in, const int* in_sizes, int n_in,
                              void* d_out, int out_size, void* d_ws, size_t ws_size,
                              hipStream_t stream) {
    const float* logits = (const float*)d_in[0];
    const float* pboxes = (const float*)d_in[1];
    const int*   labels = (const int*)d_in[2];
    const float* tboxes = (const float*)d_in[3];
    float*       out    = (float*)d_out;

    const int nqb = in_sizes[1] / 4;
    const int nt  = in_sizes[2];
    const int nc  = in_sizes[0] / nqb;

    if (nqb == NQB_C && nt == NT_C && nc == NCC) {
        const size_t tbl_bytes = (size_t)NQB_C * NCC * sizeof(float);
        float* tbl = nullptr;
        if (ws_size >= tbl_bytes) {
            tbl = (float*)d_ws;
            hipLaunchKernelGGL(cls_table_kernel, dim3((NQB_C * NCC) / 256),
                               dim3(256), 0, stream, logits, tbl);
        }
        const int nblk = (NRG * CPR) / BLK;      // 5625, exact
        hipLaunchKernelGGL(cost_fast, dim3(nblk), dim3(BLK), 0, stream,
                           tbl, logits, pboxes, labels, tboxes, out);
    } else {
        dim3 grid((nt + BLK - 1) / BLK, (nqb + QT - 1) / QT);
        size_t sm = QT * nc * sizeof(float) + QT * sizeof(float4);
        hipLaunchKernelGGL(cost_generic, grid, dim3(BLK), sm, stream,
                           logits, pboxes, labels, tboxes, out, nqb, nt, nc);
    }
}

// Round 7
// 56.464 us; speedup vs baseline: 1.0425x; 1.0425x over previous
//
#include <hip/hip_runtime.h>
#include <cmath>

// Fixed problem shape (reference setup_inputs): bs=16, nq=900, nc=80, nt=3200
#define NCC   80                 // classes
#define QT    8                  // queries per row-group
#define BLK   256                // threads per block
#define VT    4                  // targets per thread (float4 store)
#define NT_C  3200               // targets
#define NQB_C 14400              // bs*nq rows
#define CPR   (NT_C / VT)        // 800 float4-columns per row-group
#define NRG   (NQB_C / QT)       // 1800 row-groups
#define CSTR  20                 // class-table row stride in floats (16B-aligned)

typedef float f32x2 __attribute__((ext_vector_type(2)));
typedef float f32x4 __attribute__((ext_vector_type(4)));

__device__ __forceinline__ f32x2 v2(float a, float b) { f32x2 r; r.x = a; r.y = b; return r; }
__device__ __forceinline__ f32x2 vsplat(float a)      { f32x2 r; r.x = a; r.y = a; return r; }
// No packed f32 min/max on CDNA — these lower to 2x scalar v_min/v_max.
__device__ __forceinline__ f32x2 vmin2(f32x2 a, float s) { return v2(fminf(a.x, s), fminf(a.y, s)); }
__device__ __forceinline__ f32x2 vmax2(f32x2 a, float s) { return v2(fmaxf(a.x, s), fmaxf(a.y, s)); }

__device__ __forceinline__ float cls_cost(float x) {
    // 2*(pos-neg) + 2  : COST_CLASS folded + giou-rewrite constant
    const float p   = 1.0f / (1.0f + __expf(-x));
    const float om  = 1.0f - p;
    const float pos = 0.25f * om * om * (-__logf(p  + 1e-8f));
    const float neg = 0.75f * p  * p  * (-__logf(om + 1e-8f));
    return 2.0f * (pos - neg) + 2.0f;
}

// ---------------- fast kernel ----------------------------------------------
__global__ __launch_bounds__(BLK) void cost_fast(
    const float* __restrict__ logits,   // [NQB_C, NCC]
    const float* __restrict__ pboxes,   // [NQB_C, 4] cxcywh
    const int*   __restrict__ labels,   // [NT_C]
    const float* __restrict__ tboxes,   // [NT_C, 4] cxcywh
    float*       __restrict__ out)      // [NQB_C, NT_C]
{
    __shared__ float4 s_clsv[NCC * (CSTR / 4)];     // [80][20] floats
    __shared__ float4 s_qb[2 * QT];                 // cxcywh
    __shared__ float4 s_qx[2 * QT];                 // xyxy
    __shared__ float  s_qa[2 * QT];                 // area
    float* s_cls = (float*)s_clsv;

    const int  w0  = blockIdx.x * BLK;
    const int  rg0 = w0 / CPR;
    const bool two = (((w0 + BLK - 1) / CPR) != rg0);   // block spans 2 row-groups?

    // Stage transposed class table [lab][row] (only the rows we need)
    if (two) {
        for (int t = threadIdx.x; t < 2 * QT * NCC; t += BLK) {
            const int lab = t >> 4, qi = t & 15;
            const int row = (rg0 + (qi >> 3)) * QT + (qi & 7);
            s_cls[lab * CSTR + qi] = cls_cost(logits[row * NCC + lab]);
        }
    } else {
        for (int t = threadIdx.x; t < QT * NCC; t += BLK) {
            const int lab = t >> 3, qi = t & 7;
            const int row = rg0 * QT + qi;
            s_cls[lab * CSTR + qi] = cls_cost(logits[row * NCC + lab]);
        }
    }
    // Stage query geometry
    const int ng = two ? 2 * QT : QT;
    if (threadIdx.x < ng) {
        const int rg = rg0 + (threadIdx.x >> 3);
        const float4 b = ((const float4*)pboxes)[rg * QT + (threadIdx.x & 7)];
        s_qb[threadIdx.x] = b;
        s_qx[threadIdx.x] = make_float4(b.x - 0.5f * b.z, b.y - 0.5f * b.w,
                                        b.x + 0.5f * b.z, b.y + 0.5f * b.w);
        s_qa[threadIdx.x] = b.z * b.w;
    }
    __syncthreads();

    const int w  = w0 + threadIdx.x;
    const int rg = w / CPR;
    const int c  = w - rg * CPR;
    const int j  = c * VT;
    const int g8 = (rg - rg0) * QT;          // 0 or 8

    // Per-thread target data, packed as k-pairs {2kp, 2kp+1}
    const int4 lab4 = ((const int4*)labels)[c];
    const int labk[VT] = { lab4.x, lab4.y, lab4.z, lab4.w };
    f32x2 TCX[2], TCY[2], TW[2], TH[2], TX0[2], TY0[2], TX1[2], TY1[2], TA[2];
#pragma unroll
    for (int kp = 0; kp < 2; ++kp) {
        const float4 b0 = ((const float4*)tboxes)[j + 2 * kp];
        const float4 b1 = ((const float4*)tboxes)[j + 2 * kp + 1];
        TCX[kp] = v2(b0.x, b1.x);  TCY[kp] = v2(b0.y, b1.y);
        TW[kp]  = v2(b0.z, b1.z);  TH[kp]  = v2(b0.w, b1.w);
        TX0[kp] = TCX[kp] - 0.5f * TW[kp];   // pk_fma
        TX1[kp] = TCX[kp] + 0.5f * TW[kp];
        TY0[kp] = TCY[kp] - 0.5f * TH[kp];
        TY1[kp] = TCY[kp] + 0.5f * TH[kp];
        TA[kp]  = TW[kp] * TH[kp];           // pk_mul
    }

    const unsigned obase = (unsigned)(rg * QT) * NT_C + (unsigned)j;

    // Two halves of 4 queries — NOT unrolled, to cap live registers.
#pragma unroll 1
    for (int h = 0; h < 2; ++h) {
        const int qbase = g8 + h * 4;
        float4 c2v[VT];
#pragma unroll
        for (int k = 0; k < VT; ++k)
            c2v[k] = *(const float4*)&s_cls[labk[k] * CSTR + qbase];

        const unsigned offh = obase + (unsigned)h * 4u * NT_C;
#pragma unroll
        for (int q4 = 0; q4 < 4; ++q4) {
            const int    qi = qbase + q4;
            const float4 qb = s_qb[qi];
            const float4 qx = s_qx[qi];
            const float  qa = s_qa[qi];
            // splats only where packed ops need register pairs
            const f32x2 qcx = vsplat(qb.x), qcy = vsplat(qb.y);
            const f32x2 qww = vsplat(qb.z), qhh = vsplat(qb.w);
            const f32x2 qaa = vsplat(qa);
            float rr[VT];
#pragma unroll
            for (int kp = 0; kp < 2; ++kp) {
                // intersection extents (min/max scalar-split, subs packed)
                const f32x2 dx = vmin2(TX1[kp], qx.z) - vmax2(TX0[kp], qx.x);
                const f32x2 dy = vmin2(TY1[kp], qx.w) - vmax2(TY0[kp], qx.y);
                const f32x2 iw = vmax2(dx, 0.0f);
                const f32x2 ih = vmax2(dy, 0.0f);
                const f32x2 inter = iw * ih;                    // pk_mul
                const f32x2 uni   = (qaa + TA[kp]) - inter;     // pk_add, pk_sub
                const f32x2 ew    = (qww + TW[kp]) - dx;        // max=a+b-min
                const f32x2 eh    = (qhh + TH[kp]) - dy;
                const f32x2 encl  = ew * eh;
                const f32x2 ug = vmax2(uni,  1e-6f);
                const f32x2 eg = vmax2(encl, 1e-6f);
                // inter/ug + uni/eg = (inter*eg + uni*ug) / (ug*eg)
                const f32x2 num = uni * ug + inter * eg;        // pk_mul + pk_fma
                const f32x2 ue  = ug * eg;
                // L1 diffs packed; abs-adds scalar (VOP3P has no abs mods)
                const f32x2 d1 = qcx - TCX[kp];
                const f32x2 d2 = qcy - TCY[kp];
                const f32x2 d3 = qww - TW[kp];
                const f32x2 d4 = qhh - TH[kp];
                const float l1x = (fabsf(d1.x) + fabsf(d2.x)) + (fabsf(d3.x) + fabsf(d4.x));
                const float l1y = (fabsf(d1.y) + fabsf(d2.y)) + (fabsf(d3.y) + fabsf(d4.y));
                const float c2x = c2v[2 * kp + 0][q4];
                const float c2y = c2v[2 * kp + 1][q4];
                float ccx = fmaf(5.0f, l1x, c2x);
                float ccy = fmaf(5.0f, l1y, c2y);
                ccx = fmaf(num.x * __builtin_amdgcn_rcpf(ue.x), -2.0f, ccx);
                ccy = fmaf(num.y * __builtin_amdgcn_rcpf(ue.y), -2.0f, ccy);
                rr[2 * kp + 0] = ccx;
                rr[2 * kp + 1] = ccy;
            }
            f32x4 v = { rr[0], rr[1], rr[2], rr[3] };
            __builtin_nontemporal_store(
                v, (f32x4*)(out + offh + (unsigned)q4 * NT_C));
        }
    }
}

// ---------------- generic fallback ------------------------------------------
__global__ __launch_bounds__(BLK) void cost_generic(
    const float* __restrict__ logits, const float* __restrict__ pboxes,
    const int* __restrict__ labels, const float* __restrict__ tboxes,
    float* __restrict__ out, int NQB, int NT, int NC)
{
    extern __shared__ float smem[];
    float*  s_cls = smem;                  // QT*NC
    float4* s_qb  = (float4*)(smem + QT * NC);

    const int i0 = blockIdx.y * QT;
    const int j  = blockIdx.x * BLK + threadIdx.x;

    for (int t = threadIdx.x; t < QT * NC; t += BLK) {
        const int qi = i0 + t / NC;
        float v = 0.0f;
        if (qi < NQB) {
            const float x  = logits[qi * NC + (t % NC)];
            const float p  = 1.0f / (1.0f + __expf(-x));
            const float om = 1.0f - p;
            v = 0.25f * om * om * (-__logf(p + 1e-8f))
              - 0.75f * p * p * (-__logf(om + 1e-8f));
        }
        s_cls[t] = v;
    }
    if (threadIdx.x < QT) {
        const int qi = i0 + threadIdx.x;
        s_qb[threadIdx.x] = (qi < NQB) ? ((const float4*)pboxes)[qi]
                                       : make_float4(0.f, 0.f, 0.f, 0.f);
    }
    __syncthreads();
    if (j >= NT) return;

    const float4 tb = ((const float4*)tboxes)[j];
    const int   lab = labels[j];
    const float tx0 = tb.x - 0.5f * tb.z, tx1 = tb.x + 0.5f * tb.z;
    const float ty0 = tb.y - 0.5f * tb.w, ty1 = tb.y + 0.5f * tb.w;
    const float ta  = tb.z * tb.w;

#pragma unroll
    for (int q = 0; q < QT; ++q) {
        const float4 qb = s_qb[q];
        const float ccls = s_cls[q * NC + lab];
        const float l1 = fabsf(qb.x - tb.x) + fabsf(qb.y - tb.y)
                       + fabsf(qb.z - tb.z) + fabsf(qb.w - tb.w);
        const float qx0 = qb.x - 0.5f * qb.z, qx1 = qb.x + 0.5f * qb.z;
        const float qy0 = qb.y - 0.5f * qb.w, qy1 = qb.y + 0.5f * qb.w;
        const float qa  = qb.z * qb.w;
        const float ltx = fmaxf(qx0, tx0), lty = fmaxf(qy0, ty0);
        const float rbx = fminf(qx1, tx1), rby = fminf(qy1, ty1);
        const float iw = fmaxf(rbx - ltx, 0.f), ih = fmaxf(rby - lty, 0.f);
        const float inter = iw * ih;
        const float uni   = qa + ta - inter;
        const float iou   = inter * __builtin_amdgcn_rcpf(fmaxf(uni, 1e-6f));
        const float ex0 = fminf(qx0, tx0), ey0 = fminf(qy0, ty0);
        const float ex1 = fmaxf(qx1, tx1), ey1 = fmaxf(qy1, ty1);
        const float ew = fmaxf(ex1 - ex0, 0.f), eh = fmaxf(ey1 - ey0, 0.f);
        const float encl = ew * eh;
        const float giou = iou - (encl - uni) * __builtin_amdgcn_rcpf(fmaxf(encl, 1e-6f));
        float cc = 5.0f * l1 + 2.0f * ccls - 2.0f * giou;
        cc = (cc == cc) ? cc : 1.0f;
        const int qi = i0 + q;
        if (qi < NQB) out[(size_t)qi * NT + j] = cc;
    }
}

extern "C" void kernel_launch(void* const* d_in, const int* in_sizes, int n_in,
                              void* d_out, int out_size, void* d_ws, size_t ws_size,
                              hipStream_t stream) {
    const float* logits = (const float*)d_in[0];
    const float* pboxes = (const float*)d_in[1];
    const int*   labels = (const int*)d_in[2];
    const float* tboxes = (const float*)d_in[3];
    float*       out    = (float*)d_out;

    const int nqb = in_sizes[1] / 4;
    const int nt  = in_sizes[2];
    const int nc  = in_sizes[0] / nqb;

    if (nqb == NQB_C && nt == NT_C && nc == NCC) {
        const int nblk = (NRG * CPR) / BLK;      // 5625, exact
        hipLaunchKernelGGL(cost_fast, dim3(nblk), dim3(BLK), 0, stream,
                           logits, pboxes, labels, tboxes, out);
    } else {
        dim3 grid((nt + BLK - 1) / BLK, (nqb + QT - 1) / QT);
        size_t sm = QT * nc * sizeof(float) + QT * sizeof(float4);
        hipLaunchKernelGGL(cost_generic, grid, dim3(BLK), sm, stream,
                           logits, pboxes, labels, tboxes, out, nqb, nt, nc);
    }
}